// Round 5
// baseline (720.010 us; speedup 1.0000x reference)
//
#include <hip/hip_runtime.h>
#include <hip/hip_bf16.h>
#include <cstdint>
#include <cstddef>

#define T_TOK 4096
#define DM 1024
#define DFF 4096
#define NE 8
#define BT 128                        /* M tile / bucket pad */
#define BK 32
#define PADCAP (T_TOK * 2 + NE * BT)  /* 9216 */
#define MTILES (PADCAP / BT)          /* 72 */

typedef __attribute__((ext_vector_type(8))) short short8;
typedef __attribute__((ext_vector_type(4))) float f32x4;

__device__ __forceinline__ unsigned short f2bf(float f) {
  unsigned int u = __float_as_uint(f);
  return (unsigned short)((u + 0x7fff + ((u >> 16) & 1)) >> 16);
}
__device__ __forceinline__ float bf2f(unsigned short u) {
  return __uint_as_float((unsigned int)u << 16);
}

__device__ __forceinline__ void load_lds16(const void* g, void* l) {
  __builtin_amdgcn_global_load_lds(
      (const __attribute__((address_space(1))) int*)g,
      (__attribute__((address_space(3))) int*)l, 16, 0, 0);
}

// waitcnt imm (gfx9): vmcnt[3:0]|exp[6:4]|lgkm[11:8]|vmcnt_hi[15:14]
#define WAIT_VM4() __builtin_amdgcn_s_waitcnt(0x0F74) /* vmcnt(4) */
#define WAIT_VM0() __builtin_amdgcn_s_waitcnt(0x0F70) /* vmcnt(0) */
#define BARRIER()                          \
  do {                                     \
    __asm__ volatile("" ::: "memory");     \
    __builtin_amdgcn_s_barrier();          \
    __asm__ volatile("" ::: "memory");     \
  } while (0)

// ---------------- gating + x->bf16: one wave per token ----------------
__global__ __launch_bounds__(256) void gate_kernel(
    const float* __restrict__ x, const float* __restrict__ Wg,
    int* __restrict__ counts, int* __restrict__ topk_idx,
    float* __restrict__ topk_w, unsigned short* __restrict__ xb) {
  int gid = blockIdx.x * blockDim.x + threadIdx.x;
  int t = gid >> 6;
  int lane = gid & 63;
  if (t >= T_TOK) return;
  const float* xr = x + (size_t)t * DM;
  unsigned short* xbr = xb + (size_t)t * DM;
  float acc[NE];
#pragma unroll
  for (int e = 0; e < NE; ++e) acc[e] = 0.f;
#pragma unroll
  for (int j = 0; j < DM / 64; ++j) {
    int d = lane + j * 64;
    float xv = xr[d];
    xbr[d] = f2bf(xv);
    const float4* wr = (const float4*)(Wg + (size_t)d * NE);
    float4 w0 = wr[0], w1 = wr[1];
    acc[0] += xv * w0.x; acc[1] += xv * w0.y;
    acc[2] += xv * w0.z; acc[3] += xv * w0.w;
    acc[4] += xv * w1.x; acc[5] += xv * w1.y;
    acc[6] += xv * w1.z; acc[7] += xv * w1.w;
  }
#pragma unroll
  for (int off = 32; off >= 1; off >>= 1) {
#pragma unroll
    for (int e = 0; e < NE; ++e) acc[e] += __shfl_xor(acc[e], off, 64);
  }
  if (lane == 0) {
    int i0 = 0;
#pragma unroll
    for (int e = 1; e < NE; ++e)
      if (acc[e] > acc[i0]) i0 = e;
    int i1 = (i0 == 0) ? 1 : 0;
#pragma unroll
    for (int e = 0; e < NE; ++e)
      if (e != i0 && acc[e] > acc[i1]) i1 = e;
    float e1 = __expf(acc[i1] - acc[i0]);
    float inv = 1.f / (1.f + e1);
    topk_idx[t * 2] = i0;
    topk_idx[t * 2 + 1] = i1;
    topk_w[t * 2] = inv;
    topk_w[t * 2 + 1] = e1 * inv;
    atomicAdd(&counts[i0], 1);
    atomicAdd(&counts[i1], 1);
  }
}

// ---------------- routing bookkeeping ----------------
__global__ void init_kernel(int* counts, int* cursors, int* bucket_tok) {
  int i = blockIdx.x * blockDim.x + threadIdx.x;
  if (i < NE) { counts[i] = 0; cursors[i] = 0; }
  if (i < PADCAP) bucket_tok[i] = -1;
}

__global__ void offsets_kernel(const int* __restrict__ counts,
                               int* __restrict__ offsets) {
  if (threadIdx.x == 0) {
    int o = 0;
    offsets[0] = 0;
    for (int e = 0; e < NE; ++e) {
      o += (counts[e] + BT - 1) & ~(BT - 1);
      offsets[e + 1] = o;
    }
  }
}

__global__ void scatter_kernel(const int* __restrict__ topk_idx,
                               const int* __restrict__ offsets,
                               int* __restrict__ cursors,
                               int* __restrict__ bucket_tok,
                               int* __restrict__ slot_of) {
  int t = blockIdx.x * blockDim.x + threadIdx.x;
  if (t >= T_TOK) return;
#pragma unroll
  for (int k = 0; k < 2; ++k) {
    int e = topk_idx[t * 2 + k];
    int pos = atomicAdd(&cursors[e], 1);
    int slot = offsets[e] + pos;
    bucket_tok[slot] = t;
    slot_of[t * 2 + k] = slot;
  }
}

// ---------------- W [E][K][N] fp32 -> Wt [E][N][K] bf16 ----------------
// pad 67: column-read bank pattern kc*536 mod 32 = kc*24 -> 2-way (free)
__global__ __launch_bounds__(256) void transpose_cvt_kernel(
    const float* __restrict__ W, unsigned short* __restrict__ Wt,
    int K, int N) {
  __shared__ float Ls[64][67];
  int e = blockIdx.z;
  const float* We = W + (size_t)e * K * N;
  unsigned short* Wte = Wt + (size_t)e * K * N;
  int k0 = blockIdx.x * 64, n0 = blockIdx.y * 64;
  int tid = threadIdx.x;
  int kr = tid >> 4, nf = (tid & 15) * 4;
#pragma unroll
  for (int p = 0; p < 4; ++p) {
    int k = kr + p * 16;
    float4 v = *(const float4*)(We + (size_t)(k0 + k) * N + n0 + nf);
    Ls[k][nf] = v.x; Ls[k][nf + 1] = v.y;
    Ls[k][nf + 2] = v.z; Ls[k][nf + 3] = v.w;
  }
  __syncthreads();
#pragma unroll
  for (int i = 0; i < 2; ++i) {
    int id = tid + i * 256;
    int n = id >> 3, kc = id & 7;
    short8 hv;
#pragma unroll
    for (int j = 0; j < 8; ++j) hv[j] = (short)f2bf(Ls[kc * 8 + j][n]);
    *(short8*)(Wte + (size_t)(n0 + n) * K + k0 + kc * 8) = hv;
  }
}

// LDS tiles: double-buffered [128 rows][32 k] bf16 (64 B/row, 4 chunks of
// 16 B). Chunk slot s of row m holds global chunk s^(m&3) (swizzle on the
// global side; staging stays lane-contiguous, frag ds_read_b128 uniform
// 8-lanes/bank-group = the floor). 2x16 KB per operand -> 33 KB/block ->
// 4 blocks/CU (the R4 occupancy play). K-loop: issue next tile (4 instrs),
// s_waitcnt vmcnt(4), s_barrier, 1 k-step (8 ds_read_b128 + 16 MFMA),
// s_barrier.

// ---------------- MFMA GEMM1: h = relu(gather(xb) @ W1 + b1) ----------
__global__ __launch_bounds__(256, 4) void gemm1_kernel(
    const unsigned short* __restrict__ xb, const unsigned short* __restrict__ Wt1,
    const float* __restrict__ b1, const int* __restrict__ offsets,
    const int* __restrict__ bucket_tok, unsigned short* __restrict__ h) {
  int r0 = blockIdx.x * BT;
  if (r0 >= offsets[NE]) return;
  int e = 0;
  while (offsets[e + 1] <= r0) ++e;
  int n0 = blockIdx.y * 128;

  __shared__ __align__(16) short As[2 * 128 * 32];
  __shared__ __align__(16) short Bs[2 * 128 * 32];
  __shared__ int toks[BT];

  int tid = threadIdx.x;
  if (tid < BT) toks[tid] = bucket_tok[r0 + tid];
  __syncthreads();

  int lane = tid & 63, w = tid >> 6;
  int rsub = lane >> 2, kc = lane & 3;
  int jsw = (kc ^ (rsub & 3)) * 8;
  const unsigned short* ga[2];
  const unsigned short* gb[2];
#pragma unroll
  for (int i = 0; i < 2; ++i) {
    int m = w * 32 + i * 16 + rsub;
    int tk = toks[m]; if (tk < 0) tk = 0;
    ga[i] = xb + (size_t)tk * DM + jsw;
    gb[i] = Wt1 + ((size_t)e * DFF + n0 + m) * DM + jsw;
  }
  int ldsW = w * 1024 + lane * 8;

  int wm = w & 1, wn = w >> 1;
  int g = lane >> 4, l15 = lane & 15;
  int cs = (g ^ (l15 & 3)) * 8;

  f32x4 acc[4][4];
#pragma unroll
  for (int i = 0; i < 4; ++i)
#pragma unroll
    for (int jj = 0; jj < 4; ++jj) acc[i][jj] = (f32x4){0.f, 0.f, 0.f, 0.f};

#pragma unroll
  for (int i = 0; i < 2; ++i) {
    load_lds16(ga[i], &As[ldsW + i * 512]);
    load_lds16(gb[i], &Bs[ldsW + i * 512]);
  }

  int buf = 0;
  const int NIT = DM / BK;  // 32
  for (int it = 0; it < NIT; ++it) {
    if (it + 1 < NIT) {
      int ko = (it + 1) * BK;
      int dst = (buf ^ 1) * 4096 + ldsW;
#pragma unroll
      for (int i = 0; i < 2; ++i) {
        load_lds16(ga[i] + ko, &As[dst + i * 512]);
        load_lds16(gb[i] + ko, &Bs[dst + i * 512]);
      }
      WAIT_VM4();
    } else {
      WAIT_VM0();
    }
    BARRIER();
    int bb = buf * 4096;
    short8 af[4], bfr[4];
#pragma unroll
    for (int mi = 0; mi < 4; ++mi)
      af[mi] = *(const short8*)&As[bb + (wm * 64 + mi * 16 + l15) * 32 + cs];
#pragma unroll
    for (int nj = 0; nj < 4; ++nj)
      bfr[nj] = *(const short8*)&Bs[bb + (wn * 64 + nj * 16 + l15) * 32 + cs];
#pragma unroll
    for (int mi = 0; mi < 4; ++mi)
#pragma unroll
      for (int nj = 0; nj < 4; ++nj)
        acc[mi][nj] = __builtin_amdgcn_mfma_f32_16x16x32_bf16(
            af[mi], bfr[nj], acc[mi][nj], 0, 0, 0);
    BARRIER();
    buf ^= 1;
  }

  // epilogue: acc -> per-wave 8KB LDS tile (chunk-swizzled) -> dwordx4 stores
  unsigned short* wt =
      (unsigned short*)(w < 2 ? (void*)As : (void*)Bs) + (w & 1) * 4096;
  const float* b1e = b1 + (size_t)e * DFF;
#pragma unroll
  for (int nj = 0; nj < 4; ++nj) {
    int nl = nj * 16 + l15;
    float bv = b1e[n0 + wn * 64 + nl];
    int tchunk = nl >> 3, nin = nl & 7;
#pragma unroll
    for (int mi = 0; mi < 4; ++mi) {
#pragma unroll
      for (int r = 0; r < 4; ++r) {
        int ml = mi * 16 + g * 4 + r;
        float v = acc[mi][nj][r] + bv;
        wt[ml * 64 + (tchunk ^ (ml & 7)) * 8 + nin] = f2bf(fmaxf(v, 0.f));
      }
    }
  }
  int q = lane >> 3, c = lane & 7;
#pragma unroll
  for (int i = 0; i < 8; ++i) {
    int ml = i * 8 + q;
    short8 v = *(const short8*)&wt[ml * 64 + (c ^ (ml & 7)) * 8];
    *(short8*)(h + (size_t)(r0 + wm * 64 + ml) * DFF + n0 + wn * 64 + c * 8) = v;
  }
}

// ------- MFMA GEMM2: S[z][slot] = (h @ W2)(k-split z) + (z==0)*b2, bf16 ---
__global__ __launch_bounds__(256, 4) void gemm2_kernel(
    const unsigned short* __restrict__ h, const unsigned short* __restrict__ Wt2,
    const float* __restrict__ b2, const int* __restrict__ offsets,
    unsigned short* __restrict__ S) {
  int r0 = blockIdx.y * BT;
  if (r0 >= offsets[NE]) return;
  int e = 0;
  while (offsets[e + 1] <= r0) ++e;
  int n0 = (blockIdx.x & 7) * 128;
  int z = blockIdx.x >> 3;
  int kbeg = z * (DFF / 2);

  __shared__ __align__(16) short As[2 * 128 * 32];
  __shared__ __align__(16) short Bs[2 * 128 * 32];

  int tid = threadIdx.x;
  int lane = tid & 63, w = tid >> 6;
  int rsub = lane >> 2, kc = lane & 3;
  int jsw = (kc ^ (rsub & 3)) * 8;
  const unsigned short* ga[2];
  const unsigned short* gb[2];
#pragma unroll
  for (int i = 0; i < 2; ++i) {
    int m = w * 32 + i * 16 + rsub;
    ga[i] = h + ((size_t)(r0 + m)) * DFF + kbeg + jsw;
    gb[i] = Wt2 + ((size_t)e * DM + n0 + m) * DFF + kbeg + jsw;
  }
  int ldsW = w * 1024 + lane * 8;

  int wm = w & 1, wn = w >> 1;
  int g = lane >> 4, l15 = lane & 15;
  int cs = (g ^ (l15 & 3)) * 8;

  f32x4 acc[4][4];
#pragma unroll
  for (int i = 0; i < 4; ++i)
#pragma unroll
    for (int jj = 0; jj < 4; ++jj) acc[i][jj] = (f32x4){0.f, 0.f, 0.f, 0.f};

#pragma unroll
  for (int i = 0; i < 2; ++i) {
    load_lds16(ga[i], &As[ldsW + i * 512]);
    load_lds16(gb[i], &Bs[ldsW + i * 512]);
  }

  int buf = 0;
  const int NIT = (DFF / 2) / BK;  // 64
  for (int it = 0; it < NIT; ++it) {
    if (it + 1 < NIT) {
      int ko = (it + 1) * BK;
      int dst = (buf ^ 1) * 4096 + ldsW;
#pragma unroll
      for (int i = 0; i < 2; ++i) {
        load_lds16(ga[i] + ko, &As[dst + i * 512]);
        load_lds16(gb[i] + ko, &Bs[dst + i * 512]);
      }
      WAIT_VM4();
    } else {
      WAIT_VM0();
    }
    BARRIER();
    int bb = buf * 4096;
    short8 af[4], bfr[4];
#pragma unroll
    for (int mi = 0; mi < 4; ++mi)
      af[mi] = *(const short8*)&As[bb + (wm * 64 + mi * 16 + l15) * 32 + cs];
#pragma unroll
    for (int nj = 0; nj < 4; ++nj)
      bfr[nj] = *(const short8*)&Bs[bb + (wn * 64 + nj * 16 + l15) * 32 + cs];
#pragma unroll
    for (int mi = 0; mi < 4; ++mi)
#pragma unroll
      for (int nj = 0; nj < 4; ++nj)
        acc[mi][nj] = __builtin_amdgcn_mfma_f32_16x16x32_bf16(
            af[mi], bfr[nj], acc[mi][nj], 0, 0, 0);
    BARRIER();
    buf ^= 1;
  }

  unsigned short* wt =
      (unsigned short*)(w < 2 ? (void*)As : (void*)Bs) + (w & 1) * 4096;
  const float* b2e = b2 + (size_t)e * DM;
  float bscale = (z == 0) ? 1.f : 0.f;
  unsigned short* Sz = S + (size_t)z * PADCAP * DM;
#pragma unroll
  for (int nj = 0; nj < 4; ++nj) {
    int nl = nj * 16 + l15;
    float bv = b2e[n0 + wn * 64 + nl] * bscale;
    int tchunk = nl >> 3, nin = nl & 7;
#pragma unroll
    for (int mi = 0; mi < 4; ++mi) {
#pragma unroll
      for (int r = 0; r < 4; ++r) {
        int ml = mi * 16 + g * 4 + r;
        wt[ml * 64 + (tchunk ^ (ml & 7)) * 8 + nin] =
            f2bf(acc[mi][nj][r] + bv);
      }
    }
  }
  int q = lane >> 3, c = lane & 7;
#pragma unroll
  for (int i = 0; i < 8; ++i) {
    int ml = i * 8 + q;
    short8 v = *(const short8*)&wt[ml * 64 + (c ^ (ml & 7)) * 8];
    *(short8*)(Sz + (size_t)(r0 + wm * 64 + ml) * DM + n0 + wn * 64 + c * 8) =
        v;
  }
}

// ------- combine: out[t] = w0*(S0+S1)[slot0] + w1*(S0+S1)[slot1] ---------
__global__ __launch_bounds__(256) void combine_kernel(
    const unsigned short* __restrict__ S, const int* __restrict__ slot_of,
    const float* __restrict__ topk_w, float* __restrict__ out) {
  int gid = blockIdx.x * 256 + threadIdx.x;
  int t = gid >> 7;
  int c = (gid & 127) * 8;
  int s0 = slot_of[t * 2], s1 = slot_of[t * 2 + 1];
  float w0 = topk_w[t * 2], w1 = topk_w[t * 2 + 1];
  const short8 a0 = *(const short8*)(S + (size_t)s0 * DM + c);
  const short8 a1 = *(const short8*)(S + ((size_t)PADCAP + s0) * DM + c);
  const short8 b0 = *(const short8*)(S + (size_t)s1 * DM + c);
  const short8 b1 = *(const short8*)(S + ((size_t)PADCAP + s1) * DM + c);
  float o[8];
#pragma unroll
  for (int j = 0; j < 8; ++j) {
    float va = bf2f((unsigned short)a0[j]) + bf2f((unsigned short)a1[j]);
    float vb = bf2f((unsigned short)b0[j]) + bf2f((unsigned short)b1[j]);
    o[j] = w0 * va + w1 * vb;
  }
  float* op = out + (size_t)t * DM + c;
  *(float4*)op = (float4){o[0], o[1], o[2], o[3]};
  *(float4*)(op + 4) = (float4){o[4], o[5], o[6], o[7]};
}

extern "C" void kernel_launch(void* const* d_in, const int* in_sizes, int n_in,
                              void* d_out, int out_size, void* d_ws,
                              size_t ws_size, hipStream_t stream) {
  const float* x = (const float*)d_in[0];
  const float* Wg = (const float*)d_in[1];
  const float* W1 = (const float*)d_in[2];
  const float* b1 = (const float*)d_in[3];
  const float* W2 = (const float*)d_in[4];
  const float* b2 = (const float*)d_in[5];
  float* out = (float*)d_out;

  int* ws_i = (int*)d_ws;
  int* counts = ws_i;
  int* offsets = ws_i + 8;
  int* cursors = ws_i + 20;
  int* bucket_tok = ws_i + 32;                       // PADCAP
  int* topk_idx = ws_i + 32 + PADCAP;                // 2*T_TOK
  float* topk_w = (float*)(ws_i + 32 + PADCAP + 2 * T_TOK);
  int* slot_of = ws_i + 32 + PADCAP + 4 * T_TOK;     // 2*T_TOK

  const size_t XB_OFF = 1u << 20;
  const size_t WT_OFF = XB_OFF + (size_t)T_TOK * DM * 2;
  const size_t H_OFF = WT_OFF + (size_t)NE * DM * DFF * 2;
  const size_t S_OFF = H_OFF + (size_t)PADCAP * DFF * 2;
  unsigned short* xb = (unsigned short*)((char*)d_ws + XB_OFF);
  unsigned short* Wt = (unsigned short*)((char*)d_ws + WT_OFF);
  unsigned short* h = (unsigned short*)((char*)d_ws + H_OFF);
  unsigned short* S = (unsigned short*)((char*)d_ws + S_OFF);

  init_kernel<<<(PADCAP + 255) / 256, 256, 0, stream>>>(counts, cursors,
                                                        bucket_tok);
  gate_kernel<<<T_TOK / 4, 256, 0, stream>>>(x, Wg, counts, topk_idx, topk_w,
                                             xb);
  offsets_kernel<<<1, 64, 0, stream>>>(counts, offsets);
  scatter_kernel<<<T_TOK / 256, 256, 0, stream>>>(topk_idx, offsets, cursors,
                                                  bucket_tok, slot_of);
  transpose_cvt_kernel<<<dim3(DM / 64, DFF / 64, NE), 256, 0, stream>>>(
      W1, Wt, DM, DFF);
  gemm1_kernel<<<dim3(MTILES, DFF / 128), 256, 0, stream>>>(
      xb, Wt, b1, offsets, bucket_tok, h);
  transpose_cvt_kernel<<<dim3(DFF / 64, DM / 64, NE), 256, 0, stream>>>(
      W2, Wt, DFF, DM);
  gemm2_kernel<<<dim3(16, MTILES), 256, 0, stream>>>(h, Wt, b2, offsets, S);
  combine_kernel<<<(T_TOK * DM / 8) / 256, 256, 0, stream>>>(S, slot_of,
                                                             topk_w, out);
}

// Round 6
// 684.196 us; speedup vs baseline: 1.0523x; 1.0523x over previous
//
#include <hip/hip_runtime.h>
#include <hip/hip_bf16.h>
#include <cstdint>
#include <cstddef>

#define T_TOK 4096
#define DM 1024
#define DFF 4096
#define NE 8
#define BT 128                        /* M tile / bucket pad */
#define BK 64
#define PADCAP (T_TOK * 2 + NE * BT)  /* 9216 */
#define MTILES (PADCAP / BT)          /* 72 */

typedef __attribute__((ext_vector_type(8))) short short8;
typedef __attribute__((ext_vector_type(4))) float f32x4;

__device__ __forceinline__ unsigned short f2bf(float f) {
  unsigned int u = __float_as_uint(f);
  return (unsigned short)((u + 0x7fff + ((u >> 16) & 1)) >> 16);
}
__device__ __forceinline__ float bf2f(unsigned short u) {
  return __uint_as_float((unsigned int)u << 16);
}

__device__ __forceinline__ void load_lds16(const void* g, void* l) {
  __builtin_amdgcn_global_load_lds(
      (const __attribute__((address_space(1))) int*)g,
      (__attribute__((address_space(3))) int*)l, 16, 0, 0);
}

// waitcnt imm (gfx9): vmcnt[3:0]|exp[6:4]|lgkm[11:8]|vmcnt_hi[15:14]
#define WAIT_VM4() __builtin_amdgcn_s_waitcnt(0x0F74)   /* vmcnt(4) only */
#define WAIT_VM0() __builtin_amdgcn_s_waitcnt(0x0F70)   /* vmcnt(0) only */
#define WAIT_LGKM0() __builtin_amdgcn_s_waitcnt(0xC07F) /* lgkmcnt(0) only */
#define BARRIER()                          \
  do {                                     \
    __asm__ volatile("" ::: "memory");     \
    __builtin_amdgcn_s_barrier();          \
    __asm__ volatile("" ::: "memory");     \
  } while (0)

// ---------------- gating + x->bf16: one wave per token ----------------
__global__ __launch_bounds__(256) void gate_kernel(
    const float* __restrict__ x, const float* __restrict__ Wg,
    int* __restrict__ counts, int* __restrict__ topk_idx,
    float* __restrict__ topk_w, unsigned short* __restrict__ xb) {
  int gid = blockIdx.x * blockDim.x + threadIdx.x;
  int t = gid >> 6;
  int lane = gid & 63;
  if (t >= T_TOK) return;
  const float* xr = x + (size_t)t * DM;
  unsigned short* xbr = xb + (size_t)t * DM;
  float acc[NE];
#pragma unroll
  for (int e = 0; e < NE; ++e) acc[e] = 0.f;
#pragma unroll
  for (int j = 0; j < DM / 64; ++j) {
    int d = lane + j * 64;
    float xv = xr[d];
    xbr[d] = f2bf(xv);
    const float4* wr = (const float4*)(Wg + (size_t)d * NE);
    float4 w0 = wr[0], w1 = wr[1];
    acc[0] += xv * w0.x; acc[1] += xv * w0.y;
    acc[2] += xv * w0.z; acc[3] += xv * w0.w;
    acc[4] += xv * w1.x; acc[5] += xv * w1.y;
    acc[6] += xv * w1.z; acc[7] += xv * w1.w;
  }
#pragma unroll
  for (int off = 32; off >= 1; off >>= 1) {
#pragma unroll
    for (int e = 0; e < NE; ++e) acc[e] += __shfl_xor(acc[e], off, 64);
  }
  if (lane == 0) {
    int i0 = 0;
#pragma unroll
    for (int e = 1; e < NE; ++e)
      if (acc[e] > acc[i0]) i0 = e;
    int i1 = (i0 == 0) ? 1 : 0;
#pragma unroll
    for (int e = 0; e < NE; ++e)
      if (e != i0 && acc[e] > acc[i1]) i1 = e;
    float e1 = __expf(acc[i1] - acc[i0]);
    float inv = 1.f / (1.f + e1);
    topk_idx[t * 2] = i0;
    topk_idx[t * 2 + 1] = i1;
    topk_w[t * 2] = inv;
    topk_w[t * 2 + 1] = e1 * inv;
    atomicAdd(&counts[i0], 1);
    atomicAdd(&counts[i1], 1);
  }
}

// ---------------- routing bookkeeping ----------------
__global__ void init_kernel(int* counts, int* cursors, int* bucket_tok) {
  int i = blockIdx.x * blockDim.x + threadIdx.x;
  if (i < NE) { counts[i] = 0; cursors[i] = 0; }
  if (i < PADCAP) bucket_tok[i] = -1;
}

__global__ void offsets_kernel(const int* __restrict__ counts,
                               int* __restrict__ offsets) {
  if (threadIdx.x == 0) {
    int o = 0;
    offsets[0] = 0;
    for (int e = 0; e < NE; ++e) {
      o += (counts[e] + BT - 1) & ~(BT - 1);
      offsets[e + 1] = o;
    }
  }
}

__global__ void scatter_kernel(const int* __restrict__ topk_idx,
                               const int* __restrict__ offsets,
                               int* __restrict__ cursors,
                               int* __restrict__ bucket_tok,
                               int* __restrict__ slot_of) {
  int t = blockIdx.x * blockDim.x + threadIdx.x;
  if (t >= T_TOK) return;
#pragma unroll
  for (int k = 0; k < 2; ++k) {
    int e = topk_idx[t * 2 + k];
    int pos = atomicAdd(&cursors[e], 1);
    int slot = offsets[e] + pos;
    bucket_tok[slot] = t;
    slot_of[t * 2 + k] = slot;
  }
}

// -------- W [E][K][N] fp32 -> Wt in MFMA B-FRAGMENT order, bf16 --------
// Wt[((e*(K/32) + kt)*(N/16) + nt)*512 + (g*16 + l15)*8 + j] =
//   W[e][kt*32 + g*8 + j][nt*16 + l15]
// so a wave's B-frag load is ONE coalesced global_load_dwordx4 (1 KB).
__global__ __launch_bounds__(256) void transpose_cvt_kernel(
    const float* __restrict__ W, unsigned short* __restrict__ Wt,
    int K, int N) {
  __shared__ float Ls[64][67];
  int e = blockIdx.z;
  const float* We = W + (size_t)e * K * N;
  int k0 = blockIdx.x * 64, n0 = blockIdx.y * 64;
  int tid = threadIdx.x;
  int kr = tid >> 4, nf = (tid & 15) * 4;
#pragma unroll
  for (int p = 0; p < 4; ++p) {
    int k = kr + p * 16;
    float4 v = *(const float4*)(We + (size_t)(k0 + k) * N + n0 + nf);
    Ls[k][nf] = v.x; Ls[k][nf + 1] = v.y;
    Ls[k][nf + 2] = v.z; Ls[k][nf + 3] = v.w;
  }
  __syncthreads();
  int KT = K >> 5, NT = N >> 4;
#pragma unroll
  for (int i = 0; i < 2; ++i) {
    int id = tid + i * 256;
    int n = id >> 3, kc = id & 7;  // kc: 8-elem k-chunk within the 64
    short8 hv;
#pragma unroll
    for (int j = 0; j < 8; ++j) hv[j] = (short)f2bf(Ls[kc * 8 + j][n]);
    size_t dst = (((size_t)e * KT + (k0 >> 5) + (kc >> 2)) * NT + (n0 >> 4) +
                  (n >> 4)) * 512 +
                 ((kc & 3) * 16 + (n & 15)) * 8;
    *(short8*)(Wt + dst) = hv;
  }
}

// A-tile LDS: dbuf [2][128 rows][64 k] bf16 (128 B/row, 8 chunks of 16 B).
// Chunk slot s of row m holds global chunk s^(m&7) (XOR on the global read
// side: staging stays lane-contiguous, frag ds_read_b128 conflict-free —
// R3-verified 0 conflicts). B comes straight from frag-ordered Wt into
// registers (no LDS). Per iter: B(i) x8 coalesced loads, A-DMA(i+1) x4,
// s_waitcnt vmcnt(4) [FIFO drains A(i)+B(i), keeps A(i+1) in flight],
// s_barrier, frag reads + 32 MFMA, lgkmcnt(0)+s_barrier (race-safe).

// ---------------- MFMA GEMM1: h = relu(gather(xb) @ W1 + b1) ----------
__global__ __launch_bounds__(256, 3) void gemm1_kernel(
    const unsigned short* __restrict__ xb, const unsigned short* __restrict__ WtF,
    const float* __restrict__ b1, const int* __restrict__ offsets,
    const int* __restrict__ bucket_tok, unsigned short* __restrict__ h) {
  int r0 = blockIdx.x * BT;  // mtile fast => concurrent blocks share B
  if (r0 >= offsets[NE]) return;
  int e = 0;
  while (offsets[e + 1] <= r0) ++e;
  int n0 = blockIdx.y * 128;

  __shared__ __align__(16) short LB[18432];  // A dbuf 16384 | epi 4*64*72
  __shared__ int toks[BT];

  int tid = threadIdx.x;
  if (tid < BT) toks[tid] = bucket_tok[r0 + tid];
  __syncthreads();

  int lane = tid & 63, w = tid >> 6;
  int rr = lane >> 3, cc = lane & 7;
  int jsw = (cc ^ (rr & 7)) * 8;  // global-side chunk XOR (rows mod 8 = rr)
  const unsigned short* ga[4];
#pragma unroll
  for (int i = 0; i < 4; ++i) {
    int m = w * 32 + i * 8 + rr;
    int tk = toks[m]; if (tk < 0) tk = 0;
    ga[i] = xb + (size_t)tk * DM + jsw;
  }
  int ldsW = w * 2048 + lane * 8;  // lane*16B within wave's 32-row span

  int wm = w & 1, wn = w >> 1;
  int g = lane >> 4, l15 = lane & 15;
  int x7 = l15 & 7;
  // B-frag base: nt = n0/16 + wn*4 + nj ; kt = it*2 + ks
  const int KT = DM / 32, NT = DFF / 16;
  size_t bbase = (((size_t)e * KT) * NT + (n0 >> 4) + wn * 4) * 512 + lane * 8;

  f32x4 acc[4][4];
#pragma unroll
  for (int i = 0; i < 4; ++i)
#pragma unroll
    for (int jj = 0; jj < 4; ++jj) acc[i][jj] = (f32x4){0.f, 0.f, 0.f, 0.f};

  // prologue: A tile 0 -> buf 0
#pragma unroll
  for (int i = 0; i < 4; ++i) load_lds16(ga[i], &LB[ldsW + i * 512]);

  int buf = 0;
  const int NIT = DM / BK;  // 16
  for (int it = 0; it < NIT; ++it) {
    short8 bfr[2][4];
#pragma unroll
    for (int ks = 0; ks < 2; ++ks) {
      size_t kb = bbase + (size_t)(it * 2 + ks) * NT * 512;
#pragma unroll
      for (int nj = 0; nj < 4; ++nj)
        bfr[ks][nj] = *(const short8*)(WtF + kb + (size_t)nj * 512);
    }
    if (it + 1 < NIT) {
      int ko = (it + 1) * BK;
      int dst = (buf ^ 1) * 8192 + ldsW;
#pragma unroll
      for (int i = 0; i < 4; ++i) load_lds16(ga[i] + ko, &LB[dst + i * 512]);
      WAIT_VM4();
    } else {
      WAIT_VM0();
    }
    BARRIER();
    int bb = buf * 8192;
#pragma unroll
    for (int ks = 0; ks < 2; ++ks) {
      short8 af[4];
#pragma unroll
      for (int mi = 0; mi < 4; ++mi)
        af[mi] = *(const short8*)&LB[bb + (wm * 64 + mi * 16 + l15) * 64 +
                                     (((ks * 4 + g) ^ x7)) * 8];
#pragma unroll
      for (int mi = 0; mi < 4; ++mi)
#pragma unroll
        for (int nj = 0; nj < 4; ++nj)
          acc[mi][nj] = __builtin_amdgcn_mfma_f32_16x16x32_bf16(
              af[mi], bfr[ks][nj], acc[mi][nj], 0, 0, 0);
    }
    WAIT_LGKM0();
    BARRIER();
    buf ^= 1;
  }

  // epilogue: acc -> per-wave 64x72-short LDS tile (2-way writes) -> b128
  short* wt = &LB[w * 4608];
  const float* b1e = b1 + (size_t)e * DFF;
#pragma unroll
  for (int nj = 0; nj < 4; ++nj) {
    int nl = nj * 16 + l15;
    float bv = b1e[n0 + wn * 64 + nl];
#pragma unroll
    for (int mi = 0; mi < 4; ++mi) {
#pragma unroll
      for (int r = 0; r < 4; ++r) {
        int ml = mi * 16 + g * 4 + r;
        wt[ml * 72 + nl] = (short)f2bf(fmaxf(acc[mi][nj][r] + bv, 0.f));
      }
    }
  }
  // per-wave private region: same-wave RAW ordered by lgkmcnt automatically
  int q = lane >> 3, c = lane & 7;
#pragma unroll
  for (int i = 0; i < 8; ++i) {
    int ml = i * 8 + q;
    short8 v = *(const short8*)&wt[ml * 72 + c * 8];
    *(short8*)(h + (size_t)(r0 + wm * 64 + ml) * DFF + n0 + wn * 64 + c * 8) = v;
  }
}

// ------- MFMA GEMM2: S[z][slot] = (h @ W2)(k-split z) + (z==0)*b2 -------
__global__ __launch_bounds__(256, 3) void gemm2_kernel(
    const unsigned short* __restrict__ h, const unsigned short* __restrict__ WtF,
    const float* __restrict__ b2, const int* __restrict__ offsets,
    unsigned short* __restrict__ S) {
  int r0 = blockIdx.x * BT;  // mtile fast
  if (r0 >= offsets[NE]) return;
  int e = 0;
  while (offsets[e + 1] <= r0) ++e;
  int n0 = (blockIdx.y & 7) * 128;
  int z = blockIdx.y >> 3;
  int kbeg = z * (DFF / 2);

  __shared__ __align__(16) short LB[18432];

  int tid = threadIdx.x;
  int lane = tid & 63, w = tid >> 6;
  int rr = lane >> 3, cc = lane & 7;
  int jsw = (cc ^ (rr & 7)) * 8;
  const unsigned short* ga[4];
#pragma unroll
  for (int i = 0; i < 4; ++i) {
    int m = w * 32 + i * 8 + rr;
    ga[i] = h + (size_t)(r0 + m) * DFF + kbeg + jsw;
  }
  int ldsW = w * 2048 + lane * 8;

  int wm = w & 1, wn = w >> 1;
  int g = lane >> 4, l15 = lane & 15;
  int x7 = l15 & 7;
  const int KT = DFF / 32, NT = DM / 16;
  size_t bbase =
      (((size_t)e * KT + (kbeg >> 5)) * NT + (n0 >> 4) + wn * 4) * 512 +
      lane * 8;

  f32x4 acc[4][4];
#pragma unroll
  for (int i = 0; i < 4; ++i)
#pragma unroll
    for (int jj = 0; jj < 4; ++jj) acc[i][jj] = (f32x4){0.f, 0.f, 0.f, 0.f};

#pragma unroll
  for (int i = 0; i < 4; ++i) load_lds16(ga[i], &LB[ldsW + i * 512]);

  int buf = 0;
  const int NIT = (DFF / 2) / BK;  // 32
  for (int it = 0; it < NIT; ++it) {
    short8 bfr[2][4];
#pragma unroll
    for (int ks = 0; ks < 2; ++ks) {
      size_t kb = bbase + (size_t)(it * 2 + ks) * NT * 512;
#pragma unroll
      for (int nj = 0; nj < 4; ++nj)
        bfr[ks][nj] = *(const short8*)(WtF + kb + (size_t)nj * 512);
    }
    if (it + 1 < NIT) {
      int ko = (it + 1) * BK;
      int dst = (buf ^ 1) * 8192 + ldsW;
#pragma unroll
      for (int i = 0; i < 4; ++i) load_lds16(ga[i] + ko, &LB[dst + i * 512]);
      WAIT_VM4();
    } else {
      WAIT_VM0();
    }
    BARRIER();
    int bb = buf * 8192;
#pragma unroll
    for (int ks = 0; ks < 2; ++ks) {
      short8 af[4];
#pragma unroll
      for (int mi = 0; mi < 4; ++mi)
        af[mi] = *(const short8*)&LB[bb + (wm * 64 + mi * 16 + l15) * 64 +
                                     (((ks * 4 + g) ^ x7)) * 8];
#pragma unroll
      for (int mi = 0; mi < 4; ++mi)
#pragma unroll
        for (int nj = 0; nj < 4; ++nj)
          acc[mi][nj] = __builtin_amdgcn_mfma_f32_16x16x32_bf16(
              af[mi], bfr[ks][nj], acc[mi][nj], 0, 0, 0);
    }
    WAIT_LGKM0();
    BARRIER();
    buf ^= 1;
  }

  short* wt = &LB[w * 4608];
  const float* b2e = b2 + (size_t)e * DM;
  float bscale = (z == 0) ? 1.f : 0.f;
  unsigned short* Sz = S + (size_t)z * PADCAP * DM;
#pragma unroll
  for (int nj = 0; nj < 4; ++nj) {
    int nl = nj * 16 + l15;
    float bv = b2e[n0 + wn * 64 + nl] * bscale;
#pragma unroll
    for (int mi = 0; mi < 4; ++mi) {
#pragma unroll
      for (int r = 0; r < 4; ++r) {
        int ml = mi * 16 + g * 4 + r;
        wt[ml * 72 + nl] = (short)f2bf(acc[mi][nj][r] + bv);
      }
    }
  }
  int q = lane >> 3, c = lane & 7;
#pragma unroll
  for (int i = 0; i < 8; ++i) {
    int ml = i * 8 + q;
    short8 v = *(const short8*)&wt[ml * 72 + c * 8];
    *(short8*)(Sz + (size_t)(r0 + wm * 64 + ml) * DM + n0 + wn * 64 + c * 8) =
        v;
  }
}

// ------- combine: out[t] = w0*(S0+S1)[slot0] + w1*(S0+S1)[slot1] ---------
__global__ __launch_bounds__(256) void combine_kernel(
    const unsigned short* __restrict__ S, const int* __restrict__ slot_of,
    const float* __restrict__ topk_w, float* __restrict__ out) {
  int gid = blockIdx.x * 256 + threadIdx.x;
  int t = gid >> 7;
  int c = (gid & 127) * 8;
  int s0 = slot_of[t * 2], s1 = slot_of[t * 2 + 1];
  float w0 = topk_w[t * 2], w1 = topk_w[t * 2 + 1];
  const short8 a0 = *(const short8*)(S + (size_t)s0 * DM + c);
  const short8 a1 = *(const short8*)(S + ((size_t)PADCAP + s0) * DM + c);
  const short8 b0 = *(const short8*)(S + (size_t)s1 * DM + c);
  const short8 b1 = *(const short8*)(S + ((size_t)PADCAP + s1) * DM + c);
  float o[8];
#pragma unroll
  for (int j = 0; j < 8; ++j) {
    float va = bf2f((unsigned short)a0[j]) + bf2f((unsigned short)a1[j]);
    float vb = bf2f((unsigned short)b0[j]) + bf2f((unsigned short)b1[j]);
    o[j] = w0 * va + w1 * vb;
  }
  float* op = out + (size_t)t * DM + c;
  *(float4*)op = (float4){o[0], o[1], o[2], o[3]};
  *(float4*)(op + 4) = (float4){o[4], o[5], o[6], o[7]};
}

extern "C" void kernel_launch(void* const* d_in, const int* in_sizes, int n_in,
                              void* d_out, int out_size, void* d_ws,
                              size_t ws_size, hipStream_t stream) {
  const float* x = (const float*)d_in[0];
  const float* Wg = (const float*)d_in[1];
  const float* W1 = (const float*)d_in[2];
  const float* b1 = (const float*)d_in[3];
  const float* W2 = (const float*)d_in[4];
  const float* b2 = (const float*)d_in[5];
  float* out = (float*)d_out;

  int* ws_i = (int*)d_ws;
  int* counts = ws_i;
  int* offsets = ws_i + 8;
  int* cursors = ws_i + 20;
  int* bucket_tok = ws_i + 32;                       // PADCAP
  int* topk_idx = ws_i + 32 + PADCAP;                // 2*T_TOK
  float* topk_w = (float*)(ws_i + 32 + PADCAP + 2 * T_TOK);
  int* slot_of = ws_i + 32 + PADCAP + 4 * T_TOK;     // 2*T_TOK

  const size_t XB_OFF = 1u << 20;
  const size_t WT_OFF = XB_OFF + (size_t)T_TOK * DM * 2;
  const size_t H_OFF = WT_OFF + (size_t)NE * DM * DFF * 2;
  const size_t S_OFF = H_OFF + (size_t)PADCAP * DFF * 2;
  unsigned short* xb = (unsigned short*)((char*)d_ws + XB_OFF);
  unsigned short* Wt = (unsigned short*)((char*)d_ws + WT_OFF);
  unsigned short* h = (unsigned short*)((char*)d_ws + H_OFF);
  unsigned short* S = (unsigned short*)((char*)d_ws + S_OFF);

  init_kernel<<<(PADCAP + 255) / 256, 256, 0, stream>>>(counts, cursors,
                                                        bucket_tok);
  gate_kernel<<<T_TOK / 4, 256, 0, stream>>>(x, Wg, counts, topk_idx, topk_w,
                                             xb);
  offsets_kernel<<<1, 64, 0, stream>>>(counts, offsets);
  scatter_kernel<<<T_TOK / 256, 256, 0, stream>>>(topk_idx, offsets, cursors,
                                                  bucket_tok, slot_of);
  transpose_cvt_kernel<<<dim3(DM / 64, DFF / 64, NE), 256, 0, stream>>>(
      W1, Wt, DM, DFF);
  gemm1_kernel<<<dim3(MTILES, DFF / 128), 256, 0, stream>>>(
      xb, Wt, b1, offsets, bucket_tok, h);
  transpose_cvt_kernel<<<dim3(DFF / 64, DM / 64, NE), 256, 0, stream>>>(
      W2, Wt, DFF, DM);
  gemm2_kernel<<<dim3(MTILES, 16), 256, 0, stream>>>(h, Wt, b2, offsets, S);
  combine_kernel<<<(T_TOK * DM / 8) / 256, 256, 0, stream>>>(S, slot_of,
                                                             topk_w, out);
}